// Round 8
// baseline (161.423 us; speedup 1.0000x reference)
//
#include <hip/hip_runtime.h>

// Round 8: vertical-strip streaming with register carry.
// Each thread owns column j and T=4 consecutive quad rows i0..i0+3.
// Vertical reuse across iterations (register carry, no reload):
//   th/rh (tri2(i-1,j))   <- previous iteration's t2/r2
//   tA (tp[vertex(i,j)])  <- previous tC
//   p00 <- prev p10, p01 <- prev p11, pup <- prev p01
// Per-quad VMEM: 29 instrs (was ~45). The unrolled T-loop lets the compiler
// software-pipeline: iteration k+1's loads issue while k computes, keeping
// the memory pipe at high duty cycle (rounds 2-7 all burst-drained at
// <=2.8 TB/s, ~40 us).
//
// Energy collapse (verified absmax==0 rounds 1-7):
//   sum_pq coeff[p][q](Dp.Dq) = 3(|u|^2+|w|^2+u.w) + (|a|^2+|b|^2+a.b),
//   a = n1.(R1-R2), b = n2.(R1-R2), H=1.
// Adjacency (verified): quad q=(i,j), f1=tri1=i*m+j, tri2=Q+i*m+j.
//   diag : f2=tri2(i,j):   u=t1r2-t2r2, w=t1r1-t2r0; n1=N[v01], n2=N[v10]
//   horiz: f2=tri2(i-1,j): u=t1r0-t2r0, w=t1r2-t2r1; n1=N[v00], n2=N[v01]
//   vert : f2=tri2(i,j-1): u=t1r0-t2r2, w=t1r1-t2r1; n1=N[v00], n2=N[v10]
// Clamped loads only feed contributions masked by (i<m&&j<m)/(i>0)/(j>0).

#define T 4

struct __attribute__((aligned(4))) F4s { float a, b, c, d; };
struct F3 { float x, y, z; };
struct R9 { float v[9]; };
struct R6 { float v[6]; };

__device__ __forceinline__ R9 load9(const float* __restrict__ p) {
    R9 r;
    F4s u0 = *(const F4s*)p;
    F4s u1 = *(const F4s*)(p + 4);
    r.v[0] = u0.a; r.v[1] = u0.b; r.v[2] = u0.c; r.v[3] = u0.d;
    r.v[4] = u1.a; r.v[5] = u1.b; r.v[6] = u1.c; r.v[7] = u1.d;
    r.v[8] = p[8];
    return r;
}

__device__ __forceinline__ R6 load6(const float* __restrict__ p) {
    R6 r;
    F4s u = *(const F4s*)p;
    r.v[0] = u.a; r.v[1] = u.b; r.v[2] = u.c; r.v[3] = u.d;
    r.v[4] = p[4]; r.v[5] = p[5];
    return r;
}

__device__ __forceinline__ F3 load3(const float* __restrict__ p) {
    F3 r; r.x = p[0]; r.y = p[1]; r.z = p[2]; return r;
}

__device__ __forceinline__ int imin(int a, int b) { return a < b ? a : b; }
__device__ __forceinline__ int imax(int a, int b) { return a > b ? a : b; }

__device__ __forceinline__ F3 normal_of(const R9& r) {
    float e1x = r.v[0] - r.v[3], e1y = r.v[1] - r.v[4], e1z = r.v[2] - r.v[5];
    float e2x = r.v[0] - r.v[6], e2y = r.v[1] - r.v[7], e2z = r.v[2] - r.v[8];
    float nx = e1y * e2z - e1z * e2y;
    float ny = e1z * e2x - e1x * e2z;
    float nz = e1x * e2y - e1y * e2x;
    float inv = 1.0f / sqrtf(nx * nx + ny * ny + nz * nz);
    F3 o; o.x = nx * inv; o.y = ny * inv; o.z = nz * inv; return o;
}

__device__ __forceinline__ float tri_area(const F3& p, const F3& q, const F3& r) {
    float ax = q.x - p.x, ay = q.y - p.y, az = q.z - p.z;
    float bx = r.x - p.x, by = r.y - p.y, bz = r.z - p.z;
    float cx = ay * bz - az * by, cy = az * bx - ax * bz, cz = ax * by - ay * bx;
    return 0.5f * sqrtf(cx * cx + cy * cy + cz * cz);
}

__device__ __forceinline__ float edge_ew(const float* u1, const float* u2,
                                         const float* w1, const float* w2,
                                         const float* rA, const float* rB,
                                         const F3& n1, const F3& n2,
                                         const F3& pa, const F3& pb,
                                         float asum) {
    float ux = u1[0] - u2[0], uy = u1[1] - u2[1], uz = u1[2] - u2[2];
    float wx = w1[0] - w2[0], wy = w1[1] - w2[1], wz = w1[2] - w2[2];

    float d0 = rA[0] - rB[0], d1 = rA[1] - rB[1], d2 = rA[2] - rB[2];
    float d3 = rA[3] - rB[3], d4 = rA[4] - rB[4], d5 = rA[5] - rB[5];
    float d6 = rA[6] - rB[6], d7 = rA[7] - rB[7], d8 = rA[8] - rB[8];

    float ax = n1.x * d0 + n1.y * d3 + n1.z * d6;
    float ay = n1.x * d1 + n1.y * d4 + n1.z * d7;
    float az = n1.x * d2 + n1.y * d5 + n1.z * d8;
    float bx = n2.x * d0 + n2.y * d3 + n2.z * d6;
    float by = n2.x * d1 + n2.y * d4 + n2.z * d7;
    float bz = n2.x * d2 + n2.y * d5 + n2.z * d8;

    float uu = ux * ux + uy * uy + uz * uz;
    float ww = wx * wx + wy * wy + wz * wz;
    float uw = ux * wx + uy * wy + uz * wz;
    float aa = ax * ax + ay * ay + az * az;
    float bb = bx * bx + by * by + bz * bz;
    float ab = ax * bx + ay * by + az * bz;
    float energy = (3.0f * (uu + ww + uw) + (aa + bb + ab)) * (1.0f / 9.0f);

    float dx = pa.x - pb.x, dy = pa.y - pb.y, dz = pa.z - pb.z;
    return energy * (dx * dx + dy * dy + dz * dz) / asum;
}

__global__ __launch_bounds__(256) void fused_kernel(
        const float* __restrict__ tp,    // (2Q,3,3)
        const float* __restrict__ rot,   // (2Q,3,3)
        const float* __restrict__ verts, // (n*n,3)
        double* __restrict__ partials,
        int n) {
    const int m = n - 1;
    const int Q = m * m;
    const int tid = threadIdx.x;
    const int lane = tid & 63;
    const int j = blockIdx.x * 64 + lane;
    const int s = blockIdx.y * 4 + (tid >> 6);   // strip index
    const int i0 = s * T;
    const bool jv = j < m;
    const int jc = imin(j, m - 1);
    const int jl = imax(jc - 1, 0);

    // ---- strip prologue (carried registers) ----
    int im1 = imax(i0 - 1, 0);
    R9 th  = load9(tp  + (size_t)9 * (Q + im1 * m + jc));  // tri2(i0-1,j); masked if i0==0
    R9 rh  = load9(rot + (size_t)9 * (Q + im1 * m + jc));
    R9 tA  = load9(tp  + (size_t)9 * ((size_t)i0 * n + jc));       // vertex (i0,j)
    F3 p00 = load3(verts + (size_t)3 * ((size_t)i0 * n + jc));
    F3 p01 = load3(verts + (size_t)3 * ((size_t)i0 * n + jc + 1));
    F3 pup = load3(verts + (size_t)3 * ((size_t)im1 * n + jc + 1)); // (i0-1,j+1); masked if i0==0

    double term = 0.0;

#pragma unroll
    for (int t = 0; t < T; ++t) {
        int i = i0 + t;
        int ic = imin(i, m - 1);
        bool valid = jv && (i < m);

        // ---- iteration load batch ----
        size_t f1o = (size_t)9 * ((size_t)ic * m + jc);
        size_t f2o = (size_t)9 * ((size_t)Q + (size_t)ic * m + jc);
        size_t flo = (size_t)9 * ((size_t)Q + (size_t)ic * m + jl);
        R9 t1  = load9(tp  + f1o);
        R9 r1  = load9(rot + f1o);
        R9 t2  = load9(tp  + f2o);
        R9 r2  = load9(rot + f2o);
        R6 tvl = load6(tp  + flo + 3);     // tri2(i,j-1) rows 1,2
        R9 rvl = load9(rot + flo);
        R9 tB  = load9(tp  + (size_t)9 * ((size_t)ic * n + jc + 1));        // vertex (i,j+1)
        R9 tC  = load9(tp  + (size_t)9 * ((size_t)(ic + 1) * n + jc));      // vertex (i+1,j)
        F3 p10 = load3(verts + (size_t)3 * ((size_t)(ic + 1) * n + jc));
        F3 p11 = load3(verts + (size_t)3 * ((size_t)(ic + 1) * n + jc + 1));
        F3 plf = load3(verts + (size_t)3 * ((size_t)(ic + 1) * n + jl));    // (i+1,j-1); masked j>0

        // ---- compute ----
        F3 nA = normal_of(tA);
        F3 nB = normal_of(tB);
        F3 nC = normal_of(tC);
        float a1   = tri_area(p00, p10, p01);
        float a2c  = tri_area(p10, p11, p01);
        float a2up = tri_area(p00, p01, pup);
        float a2lf = tri_area(plf, p10, p00);

        float sum = edge_ew(t1.v + 6, t2.v + 6, t1.v + 3, t2.v + 0,
                            r1.v, r2.v, nB, nC, p01, p10, a1 + a2c);
        float eh  = edge_ew(t1.v + 0, th.v + 0, t1.v + 6, th.v + 3,
                            r1.v, rh.v, nA, nB, p00, p01, a1 + a2up);
        float ev  = edge_ew(t1.v + 0, tvl.v + 3, t1.v + 3, tvl.v + 0,
                            r1.v, rvl.v, nA, nC, p00, p10, a1 + a2lf);
        sum += (i > 0 ? eh : 0.0f);
        sum += (j > 0 ? ev : 0.0f);
        if (valid) term += (double)sum;

        // ---- carry for next iteration ----
        th = t2; rh = r2;
        tA = tC;
        pup = p01; p00 = p10; p01 = p11;
    }

    // ---- block reduction ----
#pragma unroll
    for (int off = 32; off > 0; off >>= 1) term += __shfl_down(term, off, 64);
    __shared__ double sred[4];
    int wid = tid >> 6;
    if (lane == 0) sred[wid] = term;
    __syncthreads();
    if (tid == 0)
        partials[blockIdx.y * gridDim.x + blockIdx.x] =
            sred[0] + sred[1] + sred[2] + sred[3];
}

__global__ __launch_bounds__(256) void finalize_kernel(
        const double* __restrict__ partials, int P, float* __restrict__ out) {
    double s = 0.0;
    for (int i = threadIdx.x; i < P; i += 256) s += partials[i];
#pragma unroll
    for (int off = 32; off > 0; off >>= 1) s += __shfl_down(s, off, 64);
    __shared__ double sred[4];
    int lane = threadIdx.x & 63, wid = threadIdx.x >> 6;
    if (lane == 0) sred[wid] = s;
    __syncthreads();
    if (threadIdx.x == 0) out[0] = (float)(sred[0] + sred[1] + sred[2] + sred[3]);
}

extern "C" void kernel_launch(void* const* d_in, const int* in_sizes, int n_in,
                              void* d_out, int out_size, void* d_ws, size_t ws_size,
                              hipStream_t stream) {
    const float* tp    = (const float*)d_in[0];
    const float* rot   = (const float*)d_in[1];
    const float* verts = (const float*)d_in[2];

    int V = in_sizes[2] / 3;
    int n = (int)(sqrtf((float)V) + 0.5f);
    int m = n - 1;

    double* partials = (double*)d_ws;
    float*  out      = (float*)d_out;

    int strips = (m + T - 1) / T;                 // 192 for m=767
    dim3 grid((m + 63) / 64, (strips + 3) / 4);   // 12 x 48
    int P = grid.x * grid.y;
    fused_kernel<<<grid, 256, 0, stream>>>(tp, rot, verts, partials, n);
    finalize_kernel<<<1, 256, 0, stream>>>(partials, P, out);
}